// Round 7
// baseline (431.557 us; speedup 1.0000x reference)
//
#include <hip/hip_runtime.h>
#include <math.h>

#define N_NODES 256
#define T_DIM   30000
#define H_DIM   512
#define L_DIM   256

// ---------------- P = I + C ----------------
__global__ void k_init_P(float* P, float* dem) {
    int t = blockIdx.x * blockDim.x + threadIdx.x; // 65536 threads
    P[t] = ((t >> 8) == (t & 255)) ? 1.0f : 0.0f;
    if (t == 0) *dem = 0.0f;
}

__global__ void k_count_edges(const int* __restrict__ idx, int E, float* P) {
    int e = blockIdx.x * blockDim.x + threadIdx.x;
    if (e < E) {
        int s = idx[e];
        int d = idx[E + e];
        atomicAdd(&P[d * N_NODES + s], 1.0f);
    }
}

__global__ void k_zero(float* p, int n) {
    int t = blockIdx.x * blockDim.x + threadIdx.x;
    if (t < n) p[t] = 0.0f;
}

// ---------------- big GEMM: Y1 = x @ Ws1a ---------------- (unchanged R6)
template<bool ATOMIC>
__global__ __launch_bounds__(256)
void k_gemm_big(const float* __restrict__ x, const float* __restrict__ W,
                float* __restrict__ outp, int kc) {
    __shared__ float xs[16 * 140];
    __shared__ float ws[16 * 132];

    const int t  = threadIdx.x;
    const int bx = blockIdx.x;
    const int by = blockIdx.y;
    const int z  = blockIdx.z;
    const int rowBase = by * 128;
    const int colBase = bx * 128;
    const int kb0  = z * kc;
    const int kend = min(kb0 + kc, T_DIM);
    const int nchunk = (kend > kb0) ? ((kend - kb0) >> 4) : 0;

    const int lr  = t >> 2;
    const int lkq = (t & 3) * 4;
    const int wkk = t >> 5;
    const int wcq = (t & 31) * 4;
    const int tx  = t & 15, ty = t >> 4;

    float acc[8][8];
    #pragma unroll
    for (int i = 0; i < 8; ++i)
        #pragma unroll
        for (int j = 0; j < 8; ++j) acc[i][j] = 0.0f;

    if (nchunk > 0) {
        float4 xa, xb, wa, wb;
        {
            const float* xp = x + (size_t)(rowBase + lr) * T_DIM + kb0 + lkq;
            xa = *(const float4*)xp;
            xb = *(const float4*)(xp + (size_t)64 * T_DIM);
            const float* wp = W + (size_t)(kb0 + wkk) * H_DIM + colBase + wcq;
            wa = *(const float4*)wp;
            wb = *(const float4*)(wp + 8 * H_DIM);
        }

        for (int c = 0; c < nchunk; ++c) {
            __syncthreads();
            xs[(lkq + 0) * 140 + lr] = xa.x;
            xs[(lkq + 1) * 140 + lr] = xa.y;
            xs[(lkq + 2) * 140 + lr] = xa.z;
            xs[(lkq + 3) * 140 + lr] = xa.w;
            xs[(lkq + 0) * 140 + lr + 64] = xb.x;
            xs[(lkq + 1) * 140 + lr + 64] = xb.y;
            xs[(lkq + 2) * 140 + lr + 64] = xb.z;
            xs[(lkq + 3) * 140 + lr + 64] = xb.w;
            *(float4*)&ws[wkk * 132 + wcq]       = wa;
            *(float4*)&ws[(wkk + 8) * 132 + wcq] = wb;
            __syncthreads();

            if (c + 1 < nchunk) {
                int kb = kb0 + (c + 1) * 16;
                const float* xp = x + (size_t)(rowBase + lr) * T_DIM + kb + lkq;
                xa = *(const float4*)xp;
                xb = *(const float4*)(xp + (size_t)64 * T_DIM);
                const float* wp = W + (size_t)(kb + wkk) * H_DIM + colBase + wcq;
                wa = *(const float4*)wp;
                wb = *(const float4*)(wp + 8 * H_DIM);
            }

            #pragma unroll
            for (int kk = 0; kk < 16; ++kk) {
                float a[8], b[8];
                *(float4*)&a[0] = *(const float4*)&xs[kk * 140 + ty * 8];
                *(float4*)&a[4] = *(const float4*)&xs[kk * 140 + ty * 8 + 4];
                *(float4*)&b[0] = *(const float4*)&ws[kk * 132 + tx * 8];
                *(float4*)&b[4] = *(const float4*)&ws[kk * 132 + tx * 8 + 4];
                #pragma unroll
                for (int i = 0; i < 8; ++i)
                    #pragma unroll
                    for (int j = 0; j < 8; ++j)
                        acc[i][j] = fmaf(a[i], b[j], acc[i][j]);
            }
        }
    }

    if (ATOMIC) {
        if (nchunk == 0) return;
        #pragma unroll
        for (int i = 0; i < 8; ++i) {
            int r = rowBase + ty * 8 + i;
            #pragma unroll
            for (int j = 0; j < 8; ++j)
                atomicAdd(&outp[r * H_DIM + colBase + tx * 8 + j], acc[i][j]);
        }
    } else {
        float* op = outp + (size_t)z * (N_NODES * H_DIM);
        #pragma unroll
        for (int i = 0; i < 8; ++i) {
            int r = rowBase + ty * 8 + i;
            *(float4*)&op[r * H_DIM + colBase + tx * 8]     = *(float4*)&acc[i][0];
            *(float4*)&op[r * H_DIM + colBase + tx * 8 + 4] = *(float4*)&acc[i][4];
        }
    }
}

// reduce split-K partials -> Y1 (32768 float4 threads)
__global__ void k_reduce(const float4* __restrict__ Y1p, float4* __restrict__ Y1,
                         int nz) {
    int i = blockIdx.x * blockDim.x + threadIdx.x;
    float4 s = Y1p[i];
    for (int z = 1; z < nz; ++z) {
        float4 v = Y1p[(size_t)z * 32768 + i];
        s.x += v.x; s.y += v.y; s.z += v.z; s.w += v.w;
    }
    Y1[i] = s;
}

// ---------------- fused row-per-block chain kernels ----------------
// One row of the 256-node graph per block; 512 threads; all intermediate
// row-vectors live in LDS; weights/activations stream from L2/L3.

__device__ __forceinline__ float block_reduce512(float v, float* red) {
    #pragma unroll
    for (int off = 32; off; off >>= 1) v += __shfl_down(v, off, 64);
    if ((threadIdx.x & 63) == 0) red[threadIdx.x >> 6] = v;
    __syncthreads();
    float s = 0.f;
    if (threadIdx.x == 0) {
        #pragma unroll
        for (int i = 0; i < 8; ++i) s += red[i];
    }
    return s;
}

__device__ __forceinline__ float sigmoidf(float x) {
    return 1.0f / (1.0f + expf(-x));
}

// F1: h1r[r,:] = relu( relu(P[r,:]@Y1 + bs1a) @ Ws1b + bs1b )
__global__ __launch_bounds__(512)
void k_f1(const float* __restrict__ P, const float* __restrict__ Y1,
          const float* __restrict__ bs1a,
          const float* __restrict__ Ws1b, const float* __restrict__ bs1b,
          float* __restrict__ h1r) {
    __shared__ float prow[256];
    __shared__ float t1[512];
    const int r = blockIdx.x, t = threadIdx.x;
    if (t < 256) prow[t] = P[r * 256 + t];
    __syncthreads();
    float acc = 0.f;
    #pragma unroll 8
    for (int k = 0; k < 256; ++k) acc = fmaf(prow[k], Y1[k * 512 + t], acc);
    t1[t] = fmaxf(acc + bs1a[t], 0.f);
    __syncthreads();
    float acc2 = 0.f;
    #pragma unroll 8
    for (int k = 0; k < 512; ++k) acc2 = fmaf(t1[k], Ws1b[k * 512 + t], acc2);
    h1r[r * 512 + t] = fmaxf(acc2 + bs1b[t], 0.f);
}

// F2: A2=P[r,:]@h1r; t2=relu(A2@Ws2a+b); feat[r,:]=t2@Ws2b+b; dem += feat.Wd
__global__ __launch_bounds__(512)
void k_f2(const float* __restrict__ P, const float* __restrict__ h1r,
          const float* __restrict__ Ws2a, const float* __restrict__ bs2a,
          const float* __restrict__ Ws2b, const float* __restrict__ bs2b,
          const float* __restrict__ Wd, float* __restrict__ feat,
          float* __restrict__ dem) {
    __shared__ float prow[256];
    __shared__ float a2[512];
    __shared__ float t2[256];
    __shared__ float red[8];
    const int r = blockIdx.x, t = threadIdx.x;
    if (t < 256) prow[t] = P[r * 256 + t];
    __syncthreads();
    float acc = 0.f;
    #pragma unroll 8
    for (int k = 0; k < 256; ++k) acc = fmaf(prow[k], h1r[k * 512 + t], acc);
    a2[t] = acc;
    __syncthreads();
    if (t < 256) {
        float s = 0.f;
        #pragma unroll 8
        for (int k = 0; k < 512; ++k) s = fmaf(a2[k], Ws2a[k * 256 + t], s);
        t2[t] = fmaxf(s + bs2a[t], 0.f);
    }
    __syncthreads();
    float p = 0.f;
    if (t < 256) {
        float s = 0.f;
        #pragma unroll 8
        for (int k = 0; k < 256; ++k) s = fmaf(t2[k], Ws2b[k * 256 + t], s);
        float f = s + bs2b[t];
        feat[r * 256 + t] = f;
        p = f * Wd[r * 256 + t];
    }
    __syncthreads();
    float tot = block_reduce512(p, red);
    if (t == 0) atomicAdd(dem, tot);
}

// F3: A3=P[r,:]@feat; t3=relu(A3@Wc1a+b); s1=relu(t3@Wc1b+b); u[r]=s1.Wc2a
__global__ __launch_bounds__(512)
void k_f3(const float* __restrict__ P, const float* __restrict__ feat,
          const float* __restrict__ Wc1a, const float* __restrict__ bc1a,
          const float* __restrict__ Wc1b, const float* __restrict__ bc1b,
          const float* __restrict__ Wc2a, float* __restrict__ u) {
    __shared__ float prow[256];
    __shared__ float a3[256];
    __shared__ float t3[512];
    __shared__ float red[8];
    const int r = blockIdx.x, t = threadIdx.x;
    if (t < 256) prow[t] = P[r * 256 + t];
    __syncthreads();
    if (t < 256) {
        float s = 0.f;
        #pragma unroll 8
        for (int k = 0; k < 256; ++k) s = fmaf(prow[k], feat[k * 256 + t], s);
        a3[t] = s;
    }
    __syncthreads();
    float s = 0.f;
    #pragma unroll 8
    for (int k = 0; k < 256; ++k) s = fmaf(a3[k], Wc1a[k * 512 + t], s);
    t3[t] = fmaxf(s + bc1a[t], 0.f);
    __syncthreads();
    float s2 = 0.f;
    #pragma unroll 8
    for (int k = 0; k < 512; ++k) s2 = fmaf(t3[k], Wc1b[k * 512 + t], s2);
    float s1 = fmaxf(s2 + bc1b[t], 0.f);
    float part = s1 * Wc2a[t];
    __syncthreads();
    float tot = block_reduce512(part, red);
    if (t == 0) u[r] = tot;
}

// F4: v = P@u per row -> region scores; block 0 emits dementia pred
__global__ __launch_bounds__(256)
void k_final(const float* __restrict__ P, const float* __restrict__ u,
             const float* __restrict__ dem,
             const float* __restrict__ bc2a, const float* __restrict__ Wc2b,
             const float* __restrict__ bc2b, const float* __restrict__ bd,
             float* __restrict__ out) {
    __shared__ float red[4];
    const int b = blockIdx.x, t = threadIdx.x;
    float pv = P[b * 256 + t] * u[t];
    #pragma unroll
    for (int off = 32; off; off >>= 1) pv += __shfl_down(pv, off, 64);
    if ((t & 63) == 0) red[t >> 6] = pv;
    __syncthreads();
    if (t == 0) {
        float v = red[0] + red[1] + red[2] + red[3];
        float h2 = fmaxf(v + bc2a[0], 0.f);
        out[1 + b] = sigmoidf(h2 * Wc2b[0] + bc2b[0]);
        if (b == 0) out[0] = sigmoidf(*dem + bd[0]);
    }
}

extern "C" void kernel_launch(void* const* d_in, const int* in_sizes, int n_in,
                              void* d_out, int out_size, void* d_ws, size_t ws_size,
                              hipStream_t stream) {
    const float* x    = (const float*)d_in[0];
    const int*   idx  = (const int*)d_in[1];
    const float* Ws1a = (const float*)d_in[3];
    const float* bs1a = (const float*)d_in[4];
    const float* Ws1b = (const float*)d_in[5];
    const float* bs1b = (const float*)d_in[6];
    const float* Ws2a = (const float*)d_in[7];
    const float* bs2a = (const float*)d_in[8];
    const float* Ws2b = (const float*)d_in[9];
    const float* bs2b = (const float*)d_in[10];
    const float* Wc1a = (const float*)d_in[11];
    const float* bc1a = (const float*)d_in[12];
    const float* Wc1b = (const float*)d_in[13];
    const float* bc1b = (const float*)d_in[14];
    const float* Wc2a = (const float*)d_in[15];
    const float* bc2a = (const float*)d_in[16];
    const float* Wc2b = (const float*)d_in[17];
    const float* bc2b = (const float*)d_in[18];
    const float* Wd   = (const float*)d_in[19];
    const float* bd   = (const float*)d_in[20];
    float* out = (float*)d_out;
    const int E = in_sizes[1] / 2;

    float* w    = (float*)d_ws;
    float* P    = w;                  // 65536
    float* Y1   = P + 65536;          // 131072
    float* h1r  = Y1 + 131072;        // 131072
    float* feat = h1r + 131072;       // 65536
    float* u    = feat + 65536;       // 256
    float* dem  = u + 256;            // 64 (dem + pad)
    float* Y1p  = dem + 64;

    // split-K slices that fit in remaining workspace
    const long long fixed = (long long)(Y1p - w);
    const long long avail = (long long)(ws_size / 4) - fixed;
    int maxsplit = (avail > 0) ? (int)(avail / 131072) : 0;
    int nz = 0, kc = 0;
    const int CH = 1875;  // 30000/16 k-chunks
    if (maxsplit >= 2) {
        int splits = maxsplit < 64 ? maxsplit : 64;
        int chunks = (CH + splits - 1) / splits;
        nz = (CH + chunks - 1) / chunks;
        kc = chunks * 16;
    }

    // P = I + C; zero dem
    k_init_P<<<256, 256, 0, stream>>>(P, dem);
    k_count_edges<<<(E + 255) / 256, 256, 0, stream>>>(idx, E, P);

    // Y1 = x @ Ws1a   (P@(x@W) == (P@x)@W)
    if (nz > 0) {
        k_gemm_big<false><<<dim3(4, 2, nz), 256, 0, stream>>>(x, Ws1a, Y1p, kc);
        k_reduce<<<128, 256, 0, stream>>>((const float4*)Y1p, (float4*)Y1, nz);
    } else {
        k_zero<<<512, 256, 0, stream>>>(Y1, N_NODES * H_DIM);
        k_gemm_big<true><<<dim3(4, 2, 63), 256, 0, stream>>>(x, Ws1a, Y1, 480);
    }

    // fused chain: 3 row-per-block kernels + final (stream order = barrier)
    k_f1<<<256, 512, 0, stream>>>(P, Y1, bs1a, Ws1b, bs1b, h1r);
    k_f2<<<256, 512, 0, stream>>>(P, h1r, Ws2a, bs2a, Ws2b, bs2b, Wd, feat, dem);
    k_f3<<<256, 512, 0, stream>>>(P, feat, Wc1a, bc1a, Wc1b, bc1b, Wc2a, u);
    k_final<<<256, 256, 0, stream>>>(P, u, dem, bc2a, Wc2b, bc2b, bd, out);
}